// Round 1
// baseline (320.549 us; speedup 1.0000x reference)
//
#include <hip/hip_runtime.h>
#include <hip/hip_bf16.h>
#include <cstdint>
#include <cstddef>

#define BB   4
#define SS   2048
#define HIDD 1024
#define NHH  16
#define HDD  64
#define MM   (BB*SS)   // 8192

typedef __bf16 bf16x8 __attribute__((ext_vector_type(8)));
typedef float  f32x4  __attribute__((ext_vector_type(4)));

__device__ __forceinline__ unsigned short f2b(float f) {
    unsigned u = __builtin_bit_cast(unsigned, f);
    return (unsigned short)((u + 0x7FFFu + ((u >> 16) & 1u)) >> 16);
}

// async global->LDS, 16B per lane. LDS dest must be wave-uniform base + lane*16.
__device__ __forceinline__ void gl_lds16(const unsigned short* g, unsigned short* l) {
    __builtin_amdgcn_global_load_lds(
        (const __attribute__((address_space(1))) void*)g,
        (__attribute__((address_space(3))) void*)l, 16, 0, 0);
}

// ---------------------------------------------------------------- fp32 -> bf16
__global__ __launch_bounds__(256) void cvt_kernel(const float* __restrict__ src,
                                                  unsigned short* __restrict__ dst, int n4) {
    int i = blockIdx.x * 256 + threadIdx.x;
    if (i < n4) {
        float4 v = reinterpret_cast<const float4*>(src)[i];
        ushort4 o;
        o.x = f2b(v.x); o.y = f2b(v.y); o.z = f2b(v.z); o.w = f2b(v.w);
        reinterpret_cast<ushort4*>(dst)[i] = o;
    }
}

// ---------------------------------------------------------------- QKV GEMM
// C = x @ W^T + b ; op = blockIdx.z selects {Q,K,V}.
// Q,K written [B,NH,S,HD]; V written transposed [B,NH,HD,S]. Q scaled by 1/8.
__global__ __launch_bounds__(256, 3) void qkv_gemm(
    const unsigned short* __restrict__ xb,
    const unsigned short* __restrict__ wb,
    const float* __restrict__ bq, const float* __restrict__ bk, const float* __restrict__ bv,
    unsigned short* __restrict__ Qb, unsigned short* __restrict__ Kb,
    unsigned short* __restrict__ Vtb)
{
    __shared__ unsigned short lA[128 * 32];
    __shared__ unsigned short lB[128 * 32];

    const int tid  = threadIdx.x;
    const int wave = tid >> 6, lane = tid & 63;
    const int lh   = lane & 15, quad = lane >> 4;
    const int op = blockIdx.z;
    const int n0 = blockIdx.x * 128;
    const int m0 = blockIdx.y * 128;
    const unsigned short* W = wb + (size_t)op * HIDD * HIDD;
    const float* bias = (op == 0) ? bq : (op == 1) ? bk : bv;

    f32x4 acc[4][4];
#pragma unroll
    for (int i = 0; i < 4; i++)
#pragma unroll
        for (int j = 0; j < 4; j++) acc[i][j] = f32x4{0.f, 0.f, 0.f, 0.f};

    const int wm = wave & 1, wn = wave >> 1;
    const int srow = tid >> 2;        // 0..63
    const int scol = (tid & 3) * 8;   // 0,8,16,24

    for (int k0 = 0; k0 < HIDD; k0 += 32) {
        gl_lds16(&xb[(size_t)(m0 + srow) * HIDD + k0 + scol],      &lA[srow * 32 + scol]);
        gl_lds16(&xb[(size_t)(m0 + 64 + srow) * HIDD + k0 + scol], &lA[(64 + srow) * 32 + scol]);
        gl_lds16(&W [(size_t)(n0 + srow) * HIDD + k0 + scol],      &lB[srow * 32 + scol]);
        gl_lds16(&W [(size_t)(n0 + 64 + srow) * HIDD + k0 + scol], &lB[(64 + srow) * 32 + scol]);
        __syncthreads();

        bf16x8 aF[4], bF[4];
#pragma unroll
        for (int i = 0; i < 4; i++)
            aF[i] = *reinterpret_cast<const bf16x8*>(&lA[(wm * 64 + i * 16 + lh) * 32 + quad * 8]);
#pragma unroll
        for (int j = 0; j < 4; j++)
            bF[j] = *reinterpret_cast<const bf16x8*>(&lB[(wn * 64 + j * 16 + lh) * 32 + quad * 8]);
#pragma unroll
        for (int i = 0; i < 4; i++)
#pragma unroll
            for (int j = 0; j < 4; j++)
                acc[i][j] = __builtin_amdgcn_mfma_f32_16x16x32_bf16(aF[i], bF[j], acc[i][j], 0, 0, 0);
        __syncthreads();
    }

    // epilogue: C/D layout col = lane&15, row = quad*4 + reg
    const float qscale = (op == 0) ? 0.125f : 1.0f;
#pragma unroll
    for (int j = 0; j < 4; j++) {
        const int n = n0 + wn * 64 + j * 16 + lh;
        const float bvv = bias[n];
        const int h = n >> 6, d = n & 63;
#pragma unroll
        for (int i = 0; i < 4; i++) {
            const int mrow = m0 + wm * 64 + i * 16 + quad * 4;
            const int b_ = mrow >> 11, s_ = mrow & 2047;  // 4 regs stay in same b
            if (op == 2) {
                unsigned short tmp[4];
#pragma unroll
                for (int r = 0; r < 4; r++) tmp[r] = f2b(acc[i][j][r] + bvv);
                size_t a = ((size_t)(b_ * NHH + h) * HDD + d) * SS + s_;
                *reinterpret_cast<ushort4*>(&Vtb[a]) = *reinterpret_cast<ushort4*>(tmp);
            } else {
                unsigned short* dst = (op == 0) ? Qb : Kb;
#pragma unroll
                for (int r = 0; r < 4; r++) {
                    float v = (acc[i][j][r] + bvv) * qscale;
                    dst[((size_t)(b_ * NHH + h) * SS + (s_ + r)) * HDD + d] = f2b(v);
                }
            }
        }
    }
}

// ---------------------------------------------------------------- flash attention
// grid (S/128, NH, B), 256 threads. Max-free online softmax (scores bounded).
__global__ __launch_bounds__(256, 2) void attn_kernel(
    const unsigned short* __restrict__ Qb,
    const unsigned short* __restrict__ Kb,
    const unsigned short* __restrict__ Vtb,
    const float* __restrict__ mask,
    float* __restrict__ out)
{
    __shared__ unsigned short lK[2][128 * 32];  // [d-half][key][32]
    __shared__ unsigned short lV[4][64 * 32];   // [key-chunk][d][32]
    __shared__ unsigned short lP[4][16 * 136];  // per-wave P row-tile (16 x 128, +8 pad)

    const int tid  = threadIdx.x;
    const int wave = tid >> 6, lane = tid & 63;
    const int lh   = lane & 15, quad = lane >> 4;
    const int qt = blockIdx.x, h = blockIdx.y, b = blockIdx.z;
    const size_t bh = (size_t)(b * NHH + h);
    const unsigned short* Qh = Qb  + bh * SS * HDD;
    const unsigned short* Kh = Kb  + bh * SS * HDD;
    const unsigned short* Vh = Vtb + bh * HDD * SS;
    const float* mk = mask + (size_t)b * SS;
    const int q0 = qt * 128;

    // Q fragments in registers: rows wave*32 + i*16 + lh, k = kk*32 + quad*8
    bf16x8 qF[2][2];
#pragma unroll
    for (int i = 0; i < 2; i++)
#pragma unroll
        for (int kk = 0; kk < 2; kk++)
            qF[i][kk] = *reinterpret_cast<const bf16x8*>(
                &Qh[(size_t)(q0 + wave * 32 + i * 16 + lh) * HDD + kk * 32 + quad * 8]);

    f32x4 oacc[2][4];
#pragma unroll
    for (int i = 0; i < 2; i++)
#pragma unroll
        for (int dj = 0; dj < 4; dj++) oacc[i][dj] = f32x4{0.f, 0.f, 0.f, 0.f};
    float lsum[2][4];
#pragma unroll
    for (int i = 0; i < 2; i++)
#pragma unroll
        for (int r = 0; r < 4; r++) lsum[i][r] = 0.f;

    const int srow = tid >> 2;        // 0..63
    const int scol = (tid & 3) * 8;

    for (int kt = 0; kt < SS / 128; kt++) {
        const int kbase = kt * 128;
        // stage K (two 32-d halves, 2 rounds each) and V^T (four 32-key chunks)
#pragma unroll
        for (int half = 0; half < 2; half++) {
            gl_lds16(&Kh[(size_t)(kbase + srow) * HDD + half * 32 + scol],
                     &lK[half][srow * 32 + scol]);
            gl_lds16(&Kh[(size_t)(kbase + 64 + srow) * HDD + half * 32 + scol],
                     &lK[half][(64 + srow) * 32 + scol]);
        }
#pragma unroll
        for (int c = 0; c < 4; c++)
            gl_lds16(&Vh[(size_t)srow * SS + kbase + c * 32 + scol],
                     &lV[c][srow * 32 + scol]);
        __syncthreads();

        float mv[8];
#pragma unroll
        for (int j = 0; j < 8; j++) mv[j] = mk[kbase + j * 16 + lh];

#pragma unroll
        for (int i = 0; i < 2; i++) {
            // scores for this 16-row q tile: S = Q K^T (Q pre-scaled by 1/8)
            f32x4 sc[8];
#pragma unroll
            for (int j = 0; j < 8; j++) {
                f32x4 s = f32x4{0.f, 0.f, 0.f, 0.f};
#pragma unroll
                for (int kk = 0; kk < 2; kk++) {
                    bf16x8 kf = *reinterpret_cast<const bf16x8*>(
                        &lK[kk][(j * 16 + lh) * 32 + quad * 8]);
                    s = __builtin_amdgcn_mfma_f32_16x16x32_bf16(qF[i][kk], kf, s, 0, 0, 0);
                }
                sc[j] = s;
            }
            // P = exp(S + mask); accumulate row-sum partials
#pragma unroll
            for (int j = 0; j < 8; j++)
#pragma unroll
                for (int r = 0; r < 4; r++) {
                    float e = __expf(sc[j][r] + mv[j]);
                    sc[j][r] = e;
                    lsum[i][r] += e;
                }
            // C-layout -> A-layout transpose through wave-local LDS
#pragma unroll
            for (int j = 0; j < 8; j++)
#pragma unroll
                for (int r = 0; r < 4; r++)
                    lP[wave][(quad * 4 + r) * 136 + j * 16 + lh] = f2b(sc[j][r]);

            // O += P V  (A = P rows lh, k = keys; B = V^T rows d, k = keys)
#pragma unroll
            for (int ks = 0; ks < 4; ks++) {
                bf16x8 ap = *reinterpret_cast<const bf16x8*>(
                    &lP[wave][lh * 136 + ks * 32 + quad * 8]);
#pragma unroll
                for (int dj = 0; dj < 4; dj++) {
                    bf16x8 vf = *reinterpret_cast<const bf16x8*>(
                        &lV[ks][(dj * 16 + lh) * 32 + quad * 8]);
                    oacc[i][dj] = __builtin_amdgcn_mfma_f32_16x16x32_bf16(ap, vf, oacc[i][dj], 0, 0, 0);
                }
            }
        }
        __syncthreads();
    }

    // finalize row sums (reduce across the 16 lanes of each quad) and store
#pragma unroll
    for (int i = 0; i < 2; i++)
#pragma unroll
        for (int r = 0; r < 4; r++) {
            float l = lsum[i][r];
            l += __shfl_xor(l, 1, 16);
            l += __shfl_xor(l, 2, 16);
            l += __shfl_xor(l, 4, 16);
            l += __shfl_xor(l, 8, 16);
            lsum[i][r] = 1.0f / l;
        }

#pragma unroll
    for (int i = 0; i < 2; i++)
#pragma unroll
        for (int dj = 0; dj < 4; dj++)
#pragma unroll
            for (int r = 0; r < 4; r++) {
                int srow_ = q0 + wave * 32 + i * 16 + quad * 4 + r;
                out[((size_t)b * SS + srow_) * HIDD + h * HDD + dj * 16 + lh] =
                    oacc[i][dj][r] * lsum[i][r];
            }
}

// ---------------------------------------------------------------- launch
extern "C" void kernel_launch(void* const* d_in, const int* in_sizes, int n_in,
                              void* d_out, int out_size, void* d_ws, size_t ws_size,
                              hipStream_t stream) {
    const float* x    = (const float*)d_in[0];
    const float* mask = (const float*)d_in[1];
    const float* Wq   = (const float*)d_in[2];
    const float* bq   = (const float*)d_in[3];
    const float* Wk   = (const float*)d_in[4];
    const float* bk   = (const float*)d_in[5];
    const float* Wv   = (const float*)d_in[6];
    const float* bv   = (const float*)d_in[7];
    float* out = (float*)d_out;
    (void)in_sizes; (void)n_in; (void)out_size; (void)ws_size;

    unsigned short* ws  = (unsigned short*)d_ws;
    unsigned short* xb  = ws;                                   // 8192*1024
    unsigned short* wb  = xb + (size_t)MM * HIDD;               // 3*1024*1024
    unsigned short* Qb  = wb + (size_t)3 * HIDD * HIDD;         // 8192*1024
    unsigned short* Kb  = Qb + (size_t)MM * HIDD;               // 8192*1024
    unsigned short* Vtb = Kb + (size_t)MM * HIDD;               // 8192*1024 (transposed)

    const int nx4 = MM * HIDD / 4;
    const int nw4 = HIDD * HIDD / 4;
    cvt_kernel<<<(nx4 + 255) / 256, 256, 0, stream>>>(x, xb, nx4);
    cvt_kernel<<<(nw4 + 255) / 256, 256, 0, stream>>>(Wq, wb, nw4);
    cvt_kernel<<<(nw4 + 255) / 256, 256, 0, stream>>>(Wk, wb + (size_t)HIDD * HIDD, nw4);
    cvt_kernel<<<(nw4 + 255) / 256, 256, 0, stream>>>(Wv, wb + (size_t)2 * HIDD * HIDD, nw4);

    qkv_gemm<<<dim3(HIDD / 128, MM / 128, 3), 256, 0, stream>>>(
        xb, wb, bq, bk, bv, Qb, Kb, Vtb);

    attn_kernel<<<dim3(SS / 128, NHH, BB), 256, 0, stream>>>(Qb, Kb, Vtb, mask, out);
}